// Round 2
// baseline (318.822 us; speedup 1.0000x reference)
//
#include <hip/hip_runtime.h>
#include <math.h>

// Time2Vec: out[b,l,d,e] = (e==0) ? x*W[d,0]+b[d,0] : sin(x*W[d,e]+b[d,e])
// B=16, L=8192, D=8, E=64. Output fp32, 67,108,864 elements (256 MiB).
//
// ROUND 2 = DIAGNOSTIC ROUND (kernel source identical to round 1).
// The timed region is fill(~169us) + kernel + N tiny harness dispatches.
// Non-fill time is ~97us but we cannot tell how much is OUR kernel vs
// harness memset/gap overhead (dispatch-ID spacing shows 4-16 extra
// dispatches per rep). The kernel is idempotent, so we launch it TWICE:
//   k = dur(this round) - dur(round 1)   [normalized by each run's fills]
// k ~= 50us  -> kernel at write-BW roofline, remaining time is harness.
// k ~= 95us  -> ~45us headroom; next round isolates store-path vs
//               load/VALU coupling with a store-only probe.

typedef float f32x4 __attribute__((ext_vector_type(4)));

__device__ __forceinline__ f32x4 t2v_point(float xv, f32x4 w4, f32x4 b4, bool keep0)
{
    xv = (xv != xv) ? 0.0f : xv;     // nan_to_num
    f32x4 y;
    y.x = fmaf(xv, w4.x, b4.x);
    y.y = fmaf(xv, w4.y, b4.y);
    y.z = fmaf(xv, w4.z, b4.z);
    y.w = fmaf(xv, w4.w, b4.w);
    y.x = keep0 ? y.x : __sinf(y.x); // global e==0 passes through affine
    y.y = __sinf(y.y);
    y.z = __sinf(y.z);
    y.w = __sinf(y.w);
    return y;
}

template<int ITERS>
__global__ __launch_bounds__(256) void t2v_kernel_unrolled(
    const float* __restrict__ x,
    const float* __restrict__ W,   // (8, 64)
    const float* __restrict__ b,   // (8, 64)
    float* __restrict__ out)
{
    constexpr int BLOCK = 256;
    // Block owns float4s [blockIdx*BLOCK*ITERS, +BLOCK*ITERS); chunk is
    // 128 rows (= 0 mod 8), so (d, quad) are per-thread constants and
    // W/b fragments live in registers for the whole kernel.
    const int base = blockIdx.x * (BLOCK * ITERS) + threadIdx.x;
    const int quad = base & 15;                 // float4 index within E=64
    const int d    = (base >> 4) & 7;           // D index

    const f32x4 w4 = reinterpret_cast<const f32x4*>(W)[d * 16 + quad];
    const f32x4 b4 = reinterpret_cast<const f32x4*>(b)[d * 16 + quad];
    const bool keep0 = (quad == 0);

    // All ITERS x-loads issued up front (addresses independent of results)
    // so the wave keeps ITERS loads outstanding instead of 1.
    float xv[ITERS];
#pragma unroll
    for (int k = 0; k < ITERS; ++k)
        xv[k] = x[(base + k * BLOCK) >> 4];

#pragma unroll
    for (int k = 0; k < ITERS; ++k) {
        const f32x4 y = t2v_point(xv[k], w4, b4, keep0);
        __builtin_nontemporal_store(y, reinterpret_cast<f32x4*>(out) + base + k * BLOCK);
    }
}

// Fallback for shapes that don't divide evenly.
__global__ __launch_bounds__(256) void t2v_kernel_gs(
    const float* __restrict__ x,
    const float* __restrict__ W,
    const float* __restrict__ b,
    float* __restrict__ out,
    int n_f4)
{
    const int tid    = blockIdx.x * blockDim.x + threadIdx.x;
    const int stride = gridDim.x * blockDim.x;
    const int quad   = tid & 15;
    const int d      = (tid >> 4) & 7;

    const f32x4 w4 = reinterpret_cast<const f32x4*>(W)[d * 16 + quad];
    const f32x4 b4 = reinterpret_cast<const f32x4*>(b)[d * 16 + quad];
    const bool keep0 = (quad == 0);

    for (int gid = tid; gid < n_f4; gid += stride) {
        const f32x4 y = t2v_point(x[gid >> 4], w4, b4, keep0);
        reinterpret_cast<f32x4*>(out)[gid] = y;
    }
}

extern "C" void kernel_launch(void* const* d_in, const int* in_sizes, int n_in,
                              void* d_out, int out_size, void* d_ws, size_t ws_size,
                              hipStream_t stream) {
    const float* x = (const float*)d_in[0];
    const float* W = (const float*)d_in[1];
    const float* b = (const float*)d_in[2];
    float* out = (float*)d_out;

    const int n_f4  = out_size / 4;   // 16,777,216 float4 stores
    constexpr int BLOCK = 256;
    constexpr int ITERS = 8;
    constexpr int CHUNK = BLOCK * ITERS;   // 2048 float4s per block

    if (n_f4 % CHUNK == 0) {
        const int grid = n_f4 / CHUNK;     // 8192 blocks for this shape
        // DIAGNOSTIC: launch twice (idempotent). dur delta vs round 1
        // == one true kernel duration, independent of harness overhead.
        t2v_kernel_unrolled<ITERS><<<grid, BLOCK, 0, stream>>>(x, W, b, out);
        t2v_kernel_unrolled<ITERS><<<grid, BLOCK, 0, stream>>>(x, W, b, out);
    } else {
        t2v_kernel_gs<<<8192, BLOCK, 0, stream>>>(x, W, b, out, n_f4);
        t2v_kernel_gs<<<8192, BLOCK, 0, stream>>>(x, W, b, out, n_f4);
    }
}

// Round 3
// 263.800 us; speedup vs baseline: 1.2086x; 1.2086x over previous
//
#include <hip/hip_runtime.h>
#include <math.h>

// Time2Vec: out[b,l,d,e] = (e==0) ? x*W[d,0]+b[d,0] : sin(x*W[d,e]+b[d,e])
// B=16, L=8192, D=8, E=64. Output fp32, 67,108,864 elements (256 MiB).
//
// Round-2 double-launch diagnostic established the budget per rep:
//   harness fill ~169us + THIS KERNEL ~52.6us + harness misc ~44us = 266us.
// Kernel runs at ~5.2 TB/s (81% of the same-run fill kernel's 6.38 TB/s
// pure-write rate). Controllable headroom <= ~10us.
//
// Round 3: revert to single launch (diagnostic done) and A/B the store
// path: NONTEMPORAL -> PLAIN stores. The 6.38 TB/s fill uses plain
// stores; NT bypasses L2 write-combining and may be the last-10us cost.
// Everything else identical to the 266us round-1 kernel.
//
// Structure (unchanged): each block owns a contiguous 2048-float4 chunk
// (128 rows = 0 mod 8) -> per-thread (d, quad) are compile-time-stable,
// W/b fragments live in registers; 8 x-loads issued up front (8
// outstanding per wave); each wave store covers 1 KiB contiguous.

typedef float f32x4 __attribute__((ext_vector_type(4)));

__device__ __forceinline__ f32x4 t2v_point(float xv, f32x4 w4, f32x4 b4, bool keep0)
{
    xv = (xv != xv) ? 0.0f : xv;     // nan_to_num
    f32x4 y;
    y.x = fmaf(xv, w4.x, b4.x);
    y.y = fmaf(xv, w4.y, b4.y);
    y.z = fmaf(xv, w4.z, b4.z);
    y.w = fmaf(xv, w4.w, b4.w);
    y.x = keep0 ? y.x : __sinf(y.x); // global e==0 passes through affine
    y.y = __sinf(y.y);
    y.z = __sinf(y.z);
    y.w = __sinf(y.w);
    return y;
}

template<int ITERS>
__global__ __launch_bounds__(256) void t2v_kernel_unrolled(
    const float* __restrict__ x,
    const float* __restrict__ W,   // (8, 64)
    const float* __restrict__ b,   // (8, 64)
    float* __restrict__ out)
{
    constexpr int BLOCK = 256;
    const int base = blockIdx.x * (BLOCK * ITERS) + threadIdx.x;
    const int quad = base & 15;                 // float4 index within E=64
    const int d    = (base >> 4) & 7;           // D index

    const f32x4 w4 = reinterpret_cast<const f32x4*>(W)[d * 16 + quad];
    const f32x4 b4 = reinterpret_cast<const f32x4*>(b)[d * 16 + quad];
    const bool keep0 = (quad == 0);

    // All ITERS x-loads issued up front (addresses independent of results)
    // so the wave keeps ITERS loads outstanding instead of 1.
    float xv[ITERS];
#pragma unroll
    for (int k = 0; k < ITERS; ++k)
        xv[k] = x[(base + k * BLOCK) >> 4];

#pragma unroll
    for (int k = 0; k < ITERS; ++k) {
        const f32x4 y = t2v_point(xv[k], w4, b4, keep0);
        reinterpret_cast<f32x4*>(out)[base + k * BLOCK] = y;   // plain store (A/B vs NT)
    }
}

// Fallback for shapes that don't divide evenly.
__global__ __launch_bounds__(256) void t2v_kernel_gs(
    const float* __restrict__ x,
    const float* __restrict__ W,
    const float* __restrict__ b,
    float* __restrict__ out,
    int n_f4)
{
    const int tid    = blockIdx.x * blockDim.x + threadIdx.x;
    const int stride = gridDim.x * blockDim.x;
    const int quad   = tid & 15;
    const int d      = (tid >> 4) & 7;

    const f32x4 w4 = reinterpret_cast<const f32x4*>(W)[d * 16 + quad];
    const f32x4 b4 = reinterpret_cast<const f32x4*>(b)[d * 16 + quad];
    const bool keep0 = (quad == 0);

    for (int gid = tid; gid < n_f4; gid += stride) {
        const f32x4 y = t2v_point(x[gid >> 4], w4, b4, keep0);
        reinterpret_cast<f32x4*>(out)[gid] = y;
    }
}

extern "C" void kernel_launch(void* const* d_in, const int* in_sizes, int n_in,
                              void* d_out, int out_size, void* d_ws, size_t ws_size,
                              hipStream_t stream) {
    const float* x = (const float*)d_in[0];
    const float* W = (const float*)d_in[1];
    const float* b = (const float*)d_in[2];
    float* out = (float*)d_out;

    const int n_f4  = out_size / 4;   // 16,777,216 float4 stores
    constexpr int BLOCK = 256;
    constexpr int ITERS = 8;
    constexpr int CHUNK = BLOCK * ITERS;   // 2048 float4s per block

    if (n_f4 % CHUNK == 0) {
        const int grid = n_f4 / CHUNK;     // 8192 blocks for this shape
        t2v_kernel_unrolled<ITERS><<<grid, BLOCK, 0, stream>>>(x, W, b, out);
    } else {
        t2v_kernel_gs<<<8192, BLOCK, 0, stream>>>(x, W, b, out, n_f4);
    }
}